// Round 3
// baseline (672.634 us; speedup 1.0000x reference)
//
#include <hip/hip_runtime.h>
#include <hip/hip_bf16.h>
#include <math.h>

#define NB 4
#define NC 16
#define NN 8192
#define NK 9
#define QSPLIT 4
#define QLEN (NN / QSPLIT)   /* 2048 candidates per quarter */
#define WIN 128              /* candidates between stack flushes */
#define NWIN (QLEN / WIN)    /* 16 windows */
#define CAP 8                /* per-lane LDS deferral stack capacity */
#define LIST 12              /* approx top-K kept (9 + 3 margin) */
#define CAND (QSPLIT * LIST) /* 48 union candidates per row */

// ---------------------------------------------------------------------------
// Kernel 0: transpose x[b][c][n] -> xt[b][n][c]; compute the numpy-replica
// f32 norm ns32[b][n]: np.sum(x*x, axis=1) == squares rounded individually,
// then sequential adds c=0..15 (strided-axis reduce: NOT pairwise, NOT fused).
// nsk = 128 + 0.5*ns is the surrogate-key offset (precision irrelevant).
// ---------------------------------------------------------------------------
__global__ void prep_kernel(const float* __restrict__ x,
                            float* __restrict__ xt,
                            float* __restrict__ ns32,
                            float* __restrict__ nsk) {
    int t = blockIdx.x * blockDim.x + threadIdx.x; // 0..32767
    int b = t >> 13;
    int m = t & (NN - 1);
    const float* xb = x + (size_t)b * NC * NN;
    float v[NC];
#pragma unroll
    for (int c = 0; c < NC; ++c) v[c] = xb[(size_t)c * NN + m]; // coalesced
    float s = __fmul_rn(v[0], v[0]);
#pragma unroll
    for (int c = 1; c < NC; ++c) s = __fadd_rn(s, __fmul_rn(v[c], v[c]));
    float* o = xt + (size_t)t * NC;
#pragma unroll
    for (int c = 0; c < NC; ++c) o[c] = v[c];
    ns32[t] = s;
    nsk[t] = 128.0f + 0.5f * s;
}

// Sorted (ascending) 12-slot u64 insert; key = (f32bits(key)<<32)|index.
__device__ __forceinline__ void insert12(unsigned long long* lst,
                                         unsigned long long key) {
#pragma unroll
    for (int i = 0; i < LIST; ++i) {
        unsigned long long a = lst[i];
        bool sm = key < a;
        unsigned long long lo = sm ? key : a;
        key = sm ? a : key;
        lst[i] = lo;
    }
}

// ---------------------------------------------------------------------------
// Kernel 1: approximate top-12 per (row, m-quarter) by the surrogate key
// 128 + 0.5*ns_m - dot(x_n, x_m)  (monotone in dist within a row; fast fmaf
// is fine — surrogate error ~1e-4 << the ~0.3 gap at the in-quarter rank-12
// boundary, so the true top-9 always survives into the union).
// ---------------------------------------------------------------------------
__global__ __launch_bounds__(64) void topk_kernel(
        const float* __restrict__ xt, const float* __restrict__ nsk,
        unsigned short* __restrict__ cand) {
    __shared__ unsigned long long stk[64 * CAP];
    const int lane = threadIdx.x;
    const int bid = blockIdx.x;
    const int q = bid & (QSPLIT - 1);
    const int rg = bid >> 2;              // 0..511
    const int row = rg * 64 + lane;       // 0..32767
    const int b = row >> 13;
    const int n = row & (NN - 1);
    const float* xb = xt + (size_t)b * NN * NC;
    const float* xrow = xb + (size_t)n * NC;
    float xr[NC];
#pragma unroll
    for (int c = 0; c < NC; ++c) xr[c] = -xrow[c];
    const float* nb = nsk + b * NN;

    unsigned long long lst[LIST];
#pragma unroll
    for (int i = 0; i < LIST; ++i) lst[i] = ~0ULL;
    unsigned long long* mystk = stk + lane * CAP;
    int cnt = 0;
    const int m0 = q * QLEN;

    for (int w = 0; w < NWIN; ++w) {
        const unsigned thr = (unsigned)(lst[LIST - 1] >> 32); // stale = superset, safe
        const int mw = m0 + w * WIN;
#pragma unroll 4
        for (int t = 0; t < WIN; ++t) {
            const int m = mw + t;
            const float* col = xb + (size_t)m * NC;  // wave-uniform address
            float a0 = nb[m];
            float a1 = 0.f;
#pragma unroll
            for (int c = 0; c < NC; c += 2) {
                a0 = fmaf(xr[c], col[c], a0);
                a1 = fmaf(xr[c + 1], col[c + 1], a1);
            }
            const float keyf = a0 + a1;              // always > 0 by construction
            const unsigned k32 = __float_as_uint(keyf);
            if (k32 < thr) {
                const unsigned long long key =
                    ((unsigned long long)k32 << 32) | (unsigned)m;
                if (cnt < CAP) { mystk[cnt] = key; ++cnt; }
                else insert12(lst, key);             // overflow fallback (rare)
            }
        }
        for (int j = 0; j < cnt; ++j) {              // flush deferred inserts
            const unsigned long long key = mystk[j];
            if ((unsigned)(key >> 32) < (unsigned)(lst[LIST - 1] >> 32))
                insert12(lst, key);
        }
        cnt = 0;
    }
    unsigned short* o = cand + (size_t)row * CAND + q * LIST;
#pragma unroll
    for (int i = 0; i < LIST; ++i) o[i] = (unsigned short)(lst[i] & 0xFFFFu);
}

// ---------------------------------------------------------------------------
// Kernel 2: re-rank the 48 union candidates with the BIT-EXACT numpy-f32
// replica distance. numpy's einsum inner loop (sum_of_products_stride0_
// contig_outcontig_two) uses npyv_muladd == FUSED multiply-add, sequential
// over c=0..15:
//   dot  = fma chain:  acc = fl(x_n[c]*x_m[c] + acc)   (single rounding/step)
//   dist = fl( fl(ns_n + ns_m) - fl(2*dot) ),  max(dist,0),  diag = -0.1
// stable (dist, idx) top-9 (jax.lax.top_k tie rule: lower index first),
// then the 16x(16x9) conv contraction + bias.
// ---------------------------------------------------------------------------
__global__ __launch_bounds__(64) void finish_kernel(
        const float* __restrict__ xt, const float* __restrict__ ns32,
        const unsigned short* __restrict__ cand,
        const float* __restrict__ W, const float* __restrict__ bias,
        float* __restrict__ out) {
    const int row = blockIdx.x * 64 + threadIdx.x; // 0..32767
    const int b = row >> 13;
    const int n = row & (NN - 1);
    const float* xb = xt + (size_t)b * NN * NC;
    const float* xrow = xb + (size_t)n * NC;
    float xv[NC];
#pragma unroll
    for (int c = 0; c < NC; ++c) xv[c] = xrow[c];
    const float nsn = ns32[row];
    const float* nsb = ns32 + b * NN;

    float d9[NK];
    int i9[NK];
#pragma unroll
    for (int i = 0; i < NK; ++i) { d9[i] = 3.0e38f; i9[i] = 0x7FFFFFFF; }

    const unsigned short* cl = cand + (size_t)row * CAND;
    for (int j = 0; j < CAND; ++j) {
        const int m = cl[j];
        const float* col = xb + (size_t)m * NC;
        float dot = 0.0f;
#pragma unroll
        for (int c = 0; c < NC; ++c)
            dot = fmaf(xv[c], col[c], dot);   // npyv_muladd replica (FMA)
        float dist = __fsub_rn(__fadd_rn(nsn, nsb[m]), __fmul_rn(2.0f, dot));
        dist = fmaxf(dist, 0.0f);
        if (m == n) dist = -0.1f;  // reference fills diagonal with -0.1

        float dk = dist;
        int ik = m;
#pragma unroll
        for (int i = 0; i < NK; ++i) { // lex (dist, idx) sorted-9 insert
            bool sm = (dk < d9[i]) || (dk == d9[i] && ik < i9[i]);
            float td = sm ? dk : d9[i];
            int ti = sm ? ik : i9[i];
            dk = sm ? d9[i] : dk;
            ik = sm ? i9[i] : ik;
            d9[i] = td;
            i9[i] = ti;
        }
    }

    float acc[NC];
#pragma unroll
    for (int o = 0; o < NC; ++o) acc[o] = bias[o];
    for (int k = 0; k < NK; ++k) {
        const float* col = xb + (size_t)i9[k] * NC;
        float cv[NC];
#pragma unroll
        for (int c = 0; c < NC; ++c) cv[c] = col[c];
#pragma unroll
        for (int o = 0; o < NC; ++o) {
            float a = acc[o];
#pragma unroll
            for (int c = 0; c < NC; ++c)
                a = fmaf(W[o * (NC * NK) + c * NK + k], cv[c], a);
            acc[o] = a;
        }
    }
    float* ob = out + (size_t)b * NC * NN + n;
#pragma unroll
    for (int o = 0; o < NC; ++o) ob[(size_t)o * NN] = acc[o];
}

extern "C" void kernel_launch(void* const* d_in, const int* in_sizes, int n_in,
                              void* d_out, int out_size, void* d_ws, size_t ws_size,
                              hipStream_t stream) {
    const float* x = (const float*)d_in[0];     // [4][16][8192]
    const float* W = (const float*)d_in[1];     // [16][16][9]
    const float* bias = (const float*)d_in[2];  // [16]
    float* out = (float*)d_out;                 // [4][16][8192]

    char* ws = (char*)d_ws;
    float* xt = (float*)ws;                                        // 2 MB
    float* ns32 = (float*)(ws + 2097152);                          // 128 KB
    float* nsk = (float*)(ws + 2097152 + 131072);                  // 128 KB
    unsigned short* cand = (unsigned short*)(ws + 2097152 + 262144); // 3 MB

    prep_kernel<<<(NB * NN) / 256, 256, 0, stream>>>(x, xt, ns32, nsk);
    topk_kernel<<<(NB * NN / 64) * QSPLIT, 64, 0, stream>>>(xt, nsk, cand);
    finish_kernel<<<NB * NN / 64, 64, 0, stream>>>(xt, ns32, cand, W, bias, out);
}

// Round 4
// 623.866 us; speedup vs baseline: 1.0782x; 1.0782x over previous
//
#include <hip/hip_runtime.h>
#include <hip/hip_bf16.h>
#include <math.h>

#define NB 4
#define NC 16
#define NN 8192
#define NK 9
#define LIST 12   /* approx top-K kept per slice (9 + 3 margin) */
#define CAP 10    /* per-lane LDS deferral stack capacity */

// ---------------------------------------------------------------------------
// Kernel 0: transpose x[b][c][n] -> xt[b][n][c]; numpy-replica f32 norm
// ns32 (squares rounded, sequential adds, no FMA); nsk = 128 + 0.5*ns is the
// always-positive surrogate-key offset.
// ---------------------------------------------------------------------------
__global__ void prep_kernel(const float* __restrict__ x,
                            float* __restrict__ xt,
                            float* __restrict__ ns32,
                            float* __restrict__ nsk) {
    int t = blockIdx.x * blockDim.x + threadIdx.x; // 0..32767
    int b = t >> 13;
    int m = t & (NN - 1);
    const float* xb = x + (size_t)b * NC * NN;
    float v[NC];
#pragma unroll
    for (int c = 0; c < NC; ++c) v[c] = xb[(size_t)c * NN + m]; // coalesced
    float s = __fmul_rn(v[0], v[0]);
#pragma unroll
    for (int c = 1; c < NC; ++c) s = __fadd_rn(s, __fmul_rn(v[c], v[c]));
    float* o = xt + (size_t)t * NC;
#pragma unroll
    for (int c = 0; c < NC; ++c) o[c] = v[c];
    ns32[t] = s;
    nsk[t] = 128.0f + 0.5f * s;
}

// Sorted (ascending) NL-slot u64 bubble insert; key = (key32<<32)|index.
template <int NL>
__device__ __forceinline__ void insert_sorted(unsigned long long* lst,
                                              unsigned long long key) {
#pragma unroll
    for (int i = 0; i < NL; ++i) {
        unsigned long long a = lst[i];
        bool sm = key < a;
        unsigned long long lo = sm ? key : a;
        key = sm ? a : key;
        lst[i] = lo;
    }
}

// ---------------------------------------------------------------------------
// Kernel 1: approximate top-12 per (row, m-slice) by the surrogate key
// 128 + 0.5*ns_m - dot(x_n, x_m) (monotone in dist within a row; diag is
// provably the slice minimum). b/q/m are uniform-by-construction (derived
// from blockIdx + loop counter, readfirstlane-pinned) so candidate-column
// loads can go to the scalar pipe; only the row vector is per-lane.
// Geometric flush windows: expected inserts/lane/window = 12*ln2 ~ 8.3,
// buffered in a lane-contiguous LDS stack to amortize insert divergence.
// ---------------------------------------------------------------------------
template <int QSPLIT>
__global__ __launch_bounds__(64) void topk_kernel(
        const float* __restrict__ xt, const float* __restrict__ nsk,
        unsigned short* __restrict__ cand) {
    constexpr int QLEN = NN / QSPLIT;
    __shared__ unsigned long long stk[CAP * 64];
    const int lane = threadIdx.x;
    const int bid = blockIdx.x;
    const int q = bid & (QSPLIT - 1);
    const int rg = bid / QSPLIT;          // 0..511, wave-uniform
    const int b = rg >> 7;                // uniform (64-row groups don't straddle batches)
    const int row = rg * 64 + lane;
    const float* xb = xt + (size_t)b * NN * NC;   // uniform base
    const float* nb = nsk + b * NN;               // uniform base
    const int n = row & (NN - 1);
    const float* xrow = xb + (size_t)n * NC;
    float xr[NC];
#pragma unroll
    for (int c = 0; c < NC; ++c) xr[c] = -xrow[c];

    unsigned long long lst[LIST];
#pragma unroll
    for (int i = 0; i < LIST; ++i) lst[i] = ~0ULL;
    const int m0 = q * QLEN;

    auto keyat = [&](int t) -> unsigned long long {
        const int mu = __builtin_amdgcn_readfirstlane(m0 + t); // pin uniform
        const float4* c4 = (const float4*)(xb + (size_t)mu * NC);
        float4 v0 = c4[0], v1 = c4[1], v2 = c4[2], v3 = c4[3];
        float a0 = nb[mu];
        float a1 = 0.f;
        a0 = fmaf(xr[0], v0.x, a0);  a1 = fmaf(xr[1], v0.y, a1);
        a0 = fmaf(xr[2], v0.z, a0);  a1 = fmaf(xr[3], v0.w, a1);
        a0 = fmaf(xr[4], v1.x, a0);  a1 = fmaf(xr[5], v1.y, a1);
        a0 = fmaf(xr[6], v1.z, a0);  a1 = fmaf(xr[7], v1.w, a1);
        a0 = fmaf(xr[8], v2.x, a0);  a1 = fmaf(xr[9], v2.y, a1);
        a0 = fmaf(xr[10], v2.z, a0); a1 = fmaf(xr[11], v2.w, a1);
        a0 = fmaf(xr[12], v3.x, a0); a1 = fmaf(xr[13], v3.y, a1);
        a0 = fmaf(xr[14], v3.z, a0); a1 = fmaf(xr[15], v3.w, a1);
        const unsigned k32 = __float_as_uint(a0 + a1); // positive by construction
        return ((unsigned long long)k32 << 32) | (unsigned)mu;
    };

    // Prologue: first 16 candidates unconditionally (builds a real threshold,
    // avoids the threshold-infinity flood).
#pragma unroll 4
    for (int t = 0; t < 16; ++t) insert_sorted<LIST>(lst, keyat(t));

    // Geometric windows [16,32), [32,64), ... [QLEN/2, QLEN).
    for (int wbeg = 16; wbeg < QLEN; wbeg <<= 1) {
        const unsigned thr = (unsigned)(lst[LIST - 1] >> 32);
        int cnt = 0;
#pragma unroll 4
        for (int t = wbeg; t < 2 * wbeg; ++t) {
            const unsigned long long key = keyat(t);
            if ((unsigned)(key >> 32) < thr) {
                if (cnt < CAP) { stk[cnt * 64 + lane] = key; ++cnt; }
                else insert_sorted<LIST>(lst, key);  // overflow fallback
            }
        }
        for (int j = 0; j < cnt; ++j) {              // flush deferred inserts
            const unsigned long long key = stk[j * 64 + lane];
            if ((unsigned)(key >> 32) < (unsigned)(lst[LIST - 1] >> 32))
                insert_sorted<LIST>(lst, key);
        }
    }

    unsigned short* o = cand + (size_t)(rg * 64 + lane) * (QSPLIT * LIST) + q * LIST;
#pragma unroll
    for (int i = 0; i < LIST; ++i) o[i] = (unsigned short)(lst[i] & 0xFFFFu);
}

// ---------------------------------------------------------------------------
// Kernel 2: exact re-rank of the CANDN union candidates with the BIT-EXACT
// numpy-f32 replica distance (verified in R3):
//   dot  = sequential fmaf chain c=0..15 (npyv_muladd)
//   dist = fl( fl(ns_n + ns_m) - fl(2*dot) ), max(dist,0), diag strictly min.
// Packed u64 keys: k32 = bits|0x80000000 (monotone for dist>=0), diag k32=0.
// Skip-guarded 9-slot insert, then the 16x(16x9) conv contraction + bias.
// ---------------------------------------------------------------------------
template <int CANDN>
__global__ __launch_bounds__(64) void finish_kernel(
        const float* __restrict__ xt, const float* __restrict__ ns32,
        const unsigned short* __restrict__ cand,
        const float* __restrict__ W, const float* __restrict__ bias,
        float* __restrict__ out) {
    const int bid = blockIdx.x;           // 0..511
    const int lane = threadIdx.x;
    const int b = bid >> 7;               // uniform
    const int row = bid * 64 + lane;      // 0..32767
    const int n = row & (NN - 1);
    const float* xb = xt + (size_t)b * NN * NC;
    const float* xrow = xb + (size_t)n * NC;
    float xv[NC];
#pragma unroll
    for (int c = 0; c < NC; ++c) xv[c] = xrow[c];
    const float nsn = ns32[row];
    const float* nsb = ns32 + b * NN;

    unsigned long long lst[NK];
#pragma unroll
    for (int i = 0; i < NK; ++i) lst[i] = ~0ULL;

    const unsigned short* cl = cand + (size_t)row * CANDN;
    for (int j = 0; j < CANDN; ++j) {
        const int m = cl[j];
        const float* col = xb + (size_t)m * NC;
        float dot = 0.0f;
#pragma unroll
        for (int c = 0; c < NC; ++c)
            dot = fmaf(xv[c], col[c], dot);   // npyv_muladd replica (FMA)
        float dist = __fsub_rn(__fadd_rn(nsn, nsb[m]), __fmul_rn(2.0f, dot));
        dist = fmaxf(dist, 0.0f);
        const unsigned k32 = (m == n) ? 0u
                                      : (__float_as_uint(dist) | 0x80000000u);
        const unsigned long long key =
            ((unsigned long long)k32 << 32) | (unsigned)m;
        if (key < lst[NK - 1]) insert_sorted<NK>(lst, key);
    }

    float acc[NC];
#pragma unroll
    for (int o = 0; o < NC; ++o) acc[o] = bias[o];
    for (int k = 0; k < NK; ++k) {
        const float* col = xb + (size_t)(lst[k] & 0xFFFFu) * NC;
        float cv[NC];
#pragma unroll
        for (int c = 0; c < NC; ++c) cv[c] = col[c];
#pragma unroll
        for (int o = 0; o < NC; ++o) {
            float a = acc[o];
#pragma unroll
            for (int c = 0; c < NC; ++c)
                a = fmaf(W[o * (NC * NK) + c * NK + k], cv[c], a);
            acc[o] = a;
        }
    }
    float* ob = out + (size_t)b * NC * NN + n;
#pragma unroll
    for (int o = 0; o < NC; ++o) ob[(size_t)o * NN] = acc[o];
}

extern "C" void kernel_launch(void* const* d_in, const int* in_sizes, int n_in,
                              void* d_out, int out_size, void* d_ws, size_t ws_size,
                              hipStream_t stream) {
    const float* x = (const float*)d_in[0];     // [4][16][8192]
    const float* W = (const float*)d_in[1];     // [16][16][9]
    const float* bias = (const float*)d_in[2];  // [16]
    float* out = (float*)d_out;                 // [4][16][8192]

    char* ws = (char*)d_ws;
    float* xt = (float*)ws;                                          // 2 MB
    float* ns32 = (float*)(ws + 2097152);                            // 128 KB
    float* nsk = (float*)(ws + 2097152 + 131072);                    // 128 KB
    unsigned short* cand = (unsigned short*)(ws + 2097152 + 262144);

    const size_t base = 2097152 + 262144;
    auto need = [&](int Q) {
        return base + (size_t)NB * NN * (size_t)(Q * LIST) * 2;
    };

    prep_kernel<<<(NB * NN) / 256, 256, 0, stream>>>(x, xt, ns32, nsk);

    if (ws_size >= need(16)) {          // 32 waves/CU
        topk_kernel<16><<<512 * 16, 64, 0, stream>>>(xt, nsk, cand);
        finish_kernel<16 * LIST><<<512, 64, 0, stream>>>(xt, ns32, cand, W, bias, out);
    } else if (ws_size >= need(8)) {    // 16 waves/CU
        topk_kernel<8><<<512 * 8, 64, 0, stream>>>(xt, nsk, cand);
        finish_kernel<8 * LIST><<<512, 64, 0, stream>>>(xt, ns32, cand, W, bias, out);
    } else {                            // 8 waves/CU (R3 config)
        topk_kernel<4><<<512 * 4, 64, 0, stream>>>(xt, nsk, cand);
        finish_kernel<4 * LIST><<<512, 64, 0, stream>>>(xt, ns32, cand, W, bias, out);
    }
}